// Round 1
// baseline (10.892 us; speedup 1.0000x reference)
//
#include <hip/hip_runtime.h>

#define B_DIM 64
#define S_DIM 512
#define C_DIM 1000
#define N_TOTAL (B_DIM * S_DIM)   // 32768
#define NBLOCKS 128
#define NTHREADS 256

// Stage 1: each thread handles one (i,j); per-block partial sum -> d_ws.
__global__ __launch_bounds__(NTHREADS) void loss_partial_kernel(
    const float* __restrict__ out,   // [B*S, C]
    const int*   __restrict__ tgt,   // [B*S]
    float*       __restrict__ partials)
{
    int idx = blockIdx.x * NTHREADS + threadIdx.x;
    float acc = 0.0f;
    // grid covers N_TOTAL exactly (128*256 = 32768), but keep the guard cheap
    if (idx < N_TOTAL) {
        int t = tgt[idx];
        float v = out[(long long)idx * C_DIM + t];
        acc = -logf(v);
    }

    // wave64 butterfly-free shfl_down reduce
    #pragma unroll
    for (int off = 32; off > 0; off >>= 1)
        acc += __shfl_down(acc, off, 64);

    __shared__ float smem[NTHREADS / 64];
    int wave = threadIdx.x >> 6;
    if ((threadIdx.x & 63) == 0) smem[wave] = acc;
    __syncthreads();

    if (threadIdx.x == 0) {
        float s = 0.0f;
        #pragma unroll
        for (int w = 0; w < NTHREADS / 64; ++w) s += smem[w];
        partials[blockIdx.x] = s;
    }
}

// Stage 2: reduce NBLOCKS partials -> d_out[0]. Single block of 128 threads.
__global__ __launch_bounds__(128) void loss_final_kernel(
    const float* __restrict__ partials,
    float*       __restrict__ out)
{
    float acc = (threadIdx.x < NBLOCKS) ? partials[threadIdx.x] : 0.0f;

    #pragma unroll
    for (int off = 32; off > 0; off >>= 1)
        acc += __shfl_down(acc, off, 64);

    __shared__ float smem[2];
    int wave = threadIdx.x >> 6;
    if ((threadIdx.x & 63) == 0) smem[wave] = acc;
    __syncthreads();

    if (threadIdx.x == 0) {
        out[0] = smem[0] + smem[1];
    }
}

extern "C" void kernel_launch(void* const* d_in, const int* in_sizes, int n_in,
                              void* d_out, int out_size, void* d_ws, size_t ws_size,
                              hipStream_t stream) {
    const float* out_probs = (const float*)d_in[0];  // [B,S,C] float32
    const int*   target    = (const int*)d_in[1];    // [B,S] integer -> int32
    float* loss = (float*)d_out;                     // scalar
    float* partials = (float*)d_ws;                  // NBLOCKS floats of scratch

    loss_partial_kernel<<<NBLOCKS, NTHREADS, 0, stream>>>(out_probs, target, partials);
    loss_final_kernel<<<1, 128, 0, stream>>>(partials, loss);
}